// Round 1
// baseline (541.036 us; speedup 1.0000x reference)
//
#include <hip/hip_runtime.h>
#include <hip/hip_bf16.h>

// AttentionBlock: GroupNorm -> QKV -> 4-head attention (S=4096, D=64) -> out proj -> +residual
// B=4, C=256, H=W=64, S=4096, N_GROUPS=32, N_HEADS=4, D_K=64

typedef __attribute__((ext_vector_type(8))) short short8;   // 8 bf16 (4 VGPRs) MFMA A/B frag
typedef __attribute__((ext_vector_type(4))) float f32x4;    // MFMA C/D frag

__device__ __forceinline__ unsigned short f2bf(float f) {
    union { float f; unsigned u; } v; v.f = f;
    unsigned r = v.u + 0x7FFF + ((v.u >> 16) & 1);
    return (unsigned short)(r >> 16);
}

// ---------------- GroupNorm stats: one block per (b,g), 8ch*4096 = 32768 elems ----------------
__global__ __launch_bounds__(1024) void k_gn_stats(const float* __restrict__ x,
                                                   float* __restrict__ stats) {
    int bg = blockIdx.x;                       // b*32+g ; group channels contiguous
    const float4* xp = (const float4*)(x + bg * 32768);
    float s1 = 0.f, s2 = 0.f;
    for (int i = threadIdx.x; i < 8192; i += 1024) {
        float4 v = xp[i];
        s1 += v.x + v.y + v.z + v.w;
        s2 += v.x*v.x + v.y*v.y + v.z*v.z + v.w*v.w;
    }
    #pragma unroll
    for (int off = 32; off; off >>= 1) {
        s1 += __shfl_down(s1, off);
        s2 += __shfl_down(s2, off);
    }
    __shared__ float r1[16], r2[16];
    int wid = threadIdx.x >> 6;
    if ((threadIdx.x & 63) == 0) { r1[wid] = s1; r2[wid] = s2; }
    __syncthreads();
    if (threadIdx.x == 0) {
        float a = 0.f, b = 0.f;
        #pragma unroll
        for (int i = 0; i < 16; ++i) { a += r1[i]; b += r2[i]; }
        float mean = a * (1.f/32768.f);
        float var  = b * (1.f/32768.f) - mean*mean;
        stats[bg*2]   = mean;
        stats[bg*2+1] = rsqrtf(var + 1e-5f);
    }
}

// ------------- convert + transpose weights to bf16 [N][K] so B-frags are contiguous -------------
__global__ void k_cvt_w(const float* __restrict__ wqkv, const float* __restrict__ wout,
                        unsigned short* __restrict__ wqkvT, unsigned short* __restrict__ woutT) {
    int i = blockIdx.x * 256 + threadIdx.x;
    if (i < 196608) {                       // w_qkv [256][768] -> [768][256]
        int k = i / 768, n = i - k * 768;
        wqkvT[n*256 + k] = f2bf(wqkv[i]);
    }
    if (i < 65536) {                        // w_out [256][256] -> [256][256]^T
        int k = i >> 8, n = i & 255;
        woutT[n*256 + k] = f2bf(wout[i]);
    }
}

// ------- normalize + transpose: x[b][c][s] fp32 -> h[b][s][c] bf16 via 64x64 LDS tile -------
__global__ __launch_bounds__(256) void k_gn_norm(
    const float* __restrict__ x, const float* __restrict__ gamma,
    const float* __restrict__ beta, const float* __restrict__ stats,
    unsigned short* __restrict__ h) {
    __shared__ unsigned short t[64][72];          // pad 8 -> decent bank spread
    int s0 = blockIdx.x * 64, c0 = blockIdx.y * 64, b = blockIdx.z;
    int tid = threadIdx.x;
    int sl = (tid & 15) * 4;                      // float4 along s
    int cr = tid >> 4;
    #pragma unroll
    for (int p = 0; p < 4; ++p) {
        int c = c0 + cr + p * 16;
        float4 v = *(const float4*)&x[(b*256 + c)*4096 + s0 + sl];
        int sg = (b*32 + (c >> 3)) * 2;
        float mean = stats[sg], rstd = stats[sg+1];
        float sa = rstd * gamma[c];
        float sb = beta[c] - mean * sa;
        ushort4 pk;
        pk.x = f2bf(v.x*sa + sb); pk.y = f2bf(v.y*sa + sb);
        pk.z = f2bf(v.z*sa + sb); pk.w = f2bf(v.w*sa + sb);
        *(ushort4*)&t[cr + p*16][sl] = pk;
    }
    __syncthreads();
    int sr = tid >> 2;                            // 0..63 (s row)
    int cc = (tid & 3) * 16;                      // 16 channels per thread
    unsigned rr[8];
    #pragma unroll
    for (int j = 0; j < 8; ++j)
        rr[j] = (unsigned)t[cc + 2*j][sr] | ((unsigned)t[cc + 2*j + 1][sr] << 16);
    unsigned short* hp = &h[(b*4096 + s0 + sr)*256 + c0];
    *(uint4*)&hp[cc]     = make_uint4(rr[0], rr[1], rr[2], rr[3]);
    *(uint4*)&hp[cc + 8] = make_uint4(rr[4], rr[5], rr[6], rr[7]);
}

// ---------------- QKV GEMM: h[16384][256] @ wqkvT -> q,k [bh][S][64], vT [bh][64][S] ----------------
__global__ __launch_bounds__(256) void k_qkv(
    const unsigned short* __restrict__ h, const unsigned short* __restrict__ wT,
    const float* __restrict__ bqkv,
    unsigned short* __restrict__ q, unsigned short* __restrict__ kk,
    unsigned short* __restrict__ vT) {
    int mt = blockIdx.x, head = blockIdx.y;
    int tid = threadIdx.x;
    int wid = tid >> 6, lane = tid & 63;
    int g = lane >> 4, li = lane & 15;
    int m0 = mt * 64 + wid * 16;
    int row = m0 + li;
    f32x4 acc[12];
    #pragma unroll
    for (int nt = 0; nt < 12; ++nt) acc[nt] = (f32x4){0.f,0.f,0.f,0.f};
    #pragma unroll
    for (int kt = 0; kt < 8; ++kt) {
        short8 a = *(const short8*)&h[row*256 + kt*32 + g*8];
        #pragma unroll
        for (int nt = 0; nt < 12; ++nt) {
            int n = head*192 + nt*16 + li;
            short8 b = *(const short8*)&wT[n*256 + kt*32 + g*8];
            acc[nt] = __builtin_amdgcn_mfma_f32_16x16x32_bf16(a, b, acc[nt], 0, 0, 0);
        }
    }
    int b = m0 >> 12;
    int s0 = m0 & 4095;
    int bh = b*4 + head;
    #pragma unroll
    for (int nt = 0; nt < 12; ++nt) {
        int ng = head*192 + nt*16 + li;
        float bias = bqkv[ng];
        int d = (nt & 3)*16 + li;
        if ((nt >> 2) == 2) {                         // V -> transposed [bh][d][s]
            ushort4 pk;
            pk.x = f2bf(acc[nt][0] + bias); pk.y = f2bf(acc[nt][1] + bias);
            pk.z = f2bf(acc[nt][2] + bias); pk.w = f2bf(acc[nt][3] + bias);
            *(ushort4*)&vT[(bh*64 + d)*4096 + s0 + g*4] = pk;
        } else if ((nt >> 2) == 0) {                  // Q (scale 1/8 folded in)
            #pragma unroll
            for (int r = 0; r < 4; ++r)
                q[(bh*4096 + s0 + g*4 + r)*64 + d] = f2bf((acc[nt][r] + bias) * 0.125f);
        } else {                                      // K
            #pragma unroll
            for (int r = 0; r < 4; ++r)
                kk[(bh*4096 + s0 + g*4 + r)*64 + d] = f2bf(acc[nt][r] + bias);
        }
    }
}

// ---------------- flash attention: per (q-tile, bh); wave = 16 q rows; KV tiles of 64 ----------------
__global__ __launch_bounds__(256) void k_attn(
    const unsigned short* __restrict__ q, const unsigned short* __restrict__ kk,
    const unsigned short* __restrict__ vT, unsigned short* __restrict__ ao) {
    __shared__ unsigned short pT[4][16][72];      // per-wave P^T [i][j], 144B rows (16B aligned)
    int qt = blockIdx.x, bh = blockIdx.y;
    int tid = threadIdx.x;
    int wid = tid >> 6, lane = tid & 63;
    int g = lane >> 4, li = lane & 15;
    int qbase = qt * 64 + wid * 16;
    int qrow = bh * 4096 + qbase + li;
    short8 bq0 = *(const short8*)&q[qrow*64 + g*8];
    short8 bq1 = *(const short8*)&q[qrow*64 + 32 + g*8];
    f32x4 o[4];
    #pragma unroll
    for (int dt = 0; dt < 4; ++dt) o[dt] = (f32x4){0.f,0.f,0.f,0.f};
    float m_run = -1e30f, l_run = 0.f;
    unsigned short* myp = &pT[wid][0][0];
    for (int kt = 0; kt < 64; ++kt) {
        int jb = kt * 64;
        f32x4 sT[4];
        #pragma unroll
        for (int f = 0; f < 4; ++f) sT[f] = (f32x4){0.f,0.f,0.f,0.f};
        #pragma unroll
        for (int f = 0; f < 4; ++f) {                 // S^T = K-tile x Q  (j rows, i cols)
            int krow = bh*4096 + jb + f*16 + li;
            short8 ka0 = *(const short8*)&kk[krow*64 + g*8];
            short8 ka1 = *(const short8*)&kk[krow*64 + 32 + g*8];
            sT[f] = __builtin_amdgcn_mfma_f32_16x16x32_bf16(ka0, bq0, sT[f], 0, 0, 0);
            sT[f] = __builtin_amdgcn_mfma_f32_16x16x32_bf16(ka1, bq1, sT[f], 0, 0, 0);
        }
        // online softmax over j; row i = li is lane-local, partials across g-groups
        float mx = -1e30f;
        #pragma unroll
        for (int f = 0; f < 4; ++f)
            #pragma unroll
            for (int r = 0; r < 4; ++r) mx = fmaxf(mx, sT[f][r]);
        mx = fmaxf(mx, __shfl_xor(mx, 16));
        mx = fmaxf(mx, __shfl_xor(mx, 32));
        float m_new = fmaxf(m_run, mx);
        float fac = __expf(m_run - m_new);
        float psum = 0.f;
        float pv[4][4];
        #pragma unroll
        for (int f = 0; f < 4; ++f)
            #pragma unroll
            for (int r = 0; r < 4; ++r) {
                float p = __expf(sT[f][r] - m_new);
                pv[f][r] = p; psum += p;
            }
        psum += __shfl_xor(psum, 16);
        psum += __shfl_xor(psum, 32);
        l_run = l_run * fac + psum;
        m_run = m_new;
        #pragma unroll
        for (int dt = 0; dt < 4; ++dt) {
            o[dt][0] *= fac; o[dt][1] *= fac; o[dt][2] *= fac; o[dt][3] *= fac;
        }
        // stage P^T bf16 in per-wave LDS (no barrier needed: wave-private region)
        #pragma unroll
        for (int f = 0; f < 4; ++f) {
            ushort4 pk;
            pk.x = f2bf(pv[f][0]); pk.y = f2bf(pv[f][1]);
            pk.z = f2bf(pv[f][2]); pk.w = f2bf(pv[f][3]);
            *(ushort4*)&myp[li*72 + f*16 + g*4] = pk;
        }
        // O^T += V^T x P^T
        #pragma unroll
        for (int ks = 0; ks < 2; ++ks) {
            short8 pb = *(const short8*)&myp[li*72 + ks*32 + g*8];
            #pragma unroll
            for (int dt = 0; dt < 4; ++dt) {
                int vrow = bh*64 + dt*16 + li;
                short8 va = *(const short8*)&vT[vrow*4096 + jb + ks*32 + g*8];
                o[dt] = __builtin_amdgcn_mfma_f32_16x16x32_bf16(va, pb, o[dt], 0, 0, 0);
            }
        }
    }
    float inv = 1.f / l_run;
    int b = bh >> 2, hh = bh & 3;
    int s = qbase + li;
    #pragma unroll
    for (int dt = 0; dt < 4; ++dt) {
        ushort4 pk;
        pk.x = f2bf(o[dt][0]*inv); pk.y = f2bf(o[dt][1]*inv);
        pk.z = f2bf(o[dt][2]*inv); pk.w = f2bf(o[dt][3]*inv);
        *(ushort4*)&ao[(b*4096 + s)*256 + hh*64 + dt*16 + g*4] = pk;
    }
}

// ---------------- out GEMM + bias + residual, transposed float4 store ----------------
__global__ __launch_bounds__(256) void k_out(
    const unsigned short* __restrict__ ao, const unsigned short* __restrict__ wT,
    const float* __restrict__ bout, const float* __restrict__ x,
    float* __restrict__ out) {
    int mt = blockIdx.x, ntb = blockIdx.y;
    int tid = threadIdx.x;
    int wid = tid >> 6, lane = tid & 63;
    int g = lane >> 4, li = lane & 15;
    int m0 = mt * 64 + wid * 16;
    int row = m0 + li;
    f32x4 acc[4];
    #pragma unroll
    for (int nt = 0; nt < 4; ++nt) acc[nt] = (f32x4){0.f,0.f,0.f,0.f};
    #pragma unroll
    for (int kt = 0; kt < 8; ++kt) {
        short8 a = *(const short8*)&ao[row*256 + kt*32 + g*8];
        #pragma unroll
        for (int nt = 0; nt < 4; ++nt) {
            int n = ntb*64 + nt*16 + li;
            short8 b = *(const short8*)&wT[n*256 + kt*32 + g*8];
            acc[nt] = __builtin_amdgcn_mfma_f32_16x16x32_bf16(a, b, acc[nt], 0, 0, 0);
        }
    }
    int b = m0 >> 12;
    int s0 = (m0 & 4095) + g*4;
    #pragma unroll
    for (int nt = 0; nt < 4; ++nt) {
        int c = ntb*64 + nt*16 + li;
        float bias = bout[c];
        int base = (b*256 + c)*4096 + s0;
        float4 xr = *(const float4*)&x[base];
        float4 ov;
        ov.x = acc[nt][0] + bias + xr.x;
        ov.y = acc[nt][1] + bias + xr.y;
        ov.z = acc[nt][2] + bias + xr.z;
        ov.w = acc[nt][3] + bias + xr.w;
        *(float4*)&out[base] = ov;
    }
}

extern "C" void kernel_launch(void* const* d_in, const int* in_sizes, int n_in,
                              void* d_out, int out_size, void* d_ws, size_t ws_size,
                              hipStream_t stream) {
    (void)in_sizes; (void)n_in; (void)out_size; (void)ws_size;
    const float* x     = (const float*)d_in[0];
    const float* gamma = (const float*)d_in[1];
    const float* beta  = (const float*)d_in[2];
    const float* wqkv  = (const float*)d_in[3];
    const float* bqkv  = (const float*)d_in[4];
    const float* wout  = (const float*)d_in[5];
    const float* bout  = (const float*)d_in[6];
    float* out = (float*)d_out;

    char* ws = (char*)d_ws;
    unsigned short* h     = (unsigned short*)(ws);                    // 8 MB  [B*S][256] bf16
    unsigned short* q     = (unsigned short*)(ws + (8u<<20));         // 8 MB  [bh][S][64]
    unsigned short* kk    = (unsigned short*)(ws + (16u<<20));        // 8 MB  [bh][S][64]
    unsigned short* vT    = (unsigned short*)(ws + (24u<<20));        // 8 MB  [bh][64][S]
    unsigned short* ao    = (unsigned short*)(ws + (32u<<20));        // 8 MB  [B*S][256]
    unsigned short* wqkvT = (unsigned short*)(ws + (40u<<20));        // 384 KB [768][256]
    unsigned short* woutT = (unsigned short*)(ws + (40u<<20) + 393216);// 128 KB [256][256]
    float*          stats = (float*)(ws + (40u<<20) + 524288);        // 1 KB

    k_gn_stats<<<128, 1024, 0, stream>>>(x, stats);
    k_cvt_w<<<768, 256, 0, stream>>>(wqkv, wout, wqkvT, woutT);
    k_gn_norm<<<dim3(64, 4, 4), 256, 0, stream>>>(x, gamma, beta, stats, h);
    k_qkv<<<dim3(256, 4), 256, 0, stream>>>(h, wqkvT, bqkv, q, kk, vT);
    k_attn<<<dim3(64, 16), 256, 0, stream>>>(q, kk, vT, ao);
    k_out<<<dim3(256, 4), 256, 0, stream>>>(ao, woutT, bout, x, out);
}

// Round 2
// 194.824 us; speedup vs baseline: 2.7771x; 2.7771x over previous
//
#include <hip/hip_runtime.h>
#include <hip/hip_bf16.h>

// AttentionBlock: GroupNorm -> QKV -> 4-head attention (S=4096, D=64) -> out proj -> +residual
// B=4, C=256, H=W=64, S=4096, N_GROUPS=32, N_HEADS=4, D_K=64

typedef __attribute__((ext_vector_type(8))) short short8;   // 8 bf16 (4 VGPRs) MFMA A/B frag
typedef __attribute__((ext_vector_type(4))) float f32x4;    // MFMA C/D frag

__device__ __forceinline__ unsigned short f2bf(float f) {
    union { float f; unsigned u; } v; v.f = f;
    unsigned r = v.u + 0x7FFF + ((v.u >> 16) & 1);
    return (unsigned short)(r >> 16);
}

__device__ __forceinline__ unsigned cvt_pk_bf16(float lo, float hi) {
    unsigned r;
    asm("v_cvt_pk_bf16_f32 %0, %1, %2" : "=v"(r) : "v"(lo), "v"(hi));
    return r;
}

__device__ __forceinline__ float fexp2(float x) {   // D = 2^S0
    float r;
    asm("v_exp_f32 %0, %1" : "=v"(r) : "v"(x));
    return r;
}

__device__ __forceinline__ void gl_lds16(const void* g, void* l) {
    __builtin_amdgcn_global_load_lds(
        (const __attribute__((address_space(1))) void*)(g),
        (__attribute__((address_space(3))) void*)(l), 16, 0, 0);
}

// ---------------- GroupNorm stats: one block per (b,g), 8ch*4096 = 32768 elems ----------------
__global__ __launch_bounds__(1024) void k_gn_stats(const float* __restrict__ x,
                                                   float* __restrict__ stats) {
    int bg = blockIdx.x;                       // b*32+g ; group channels contiguous
    const float4* xp = (const float4*)(x + bg * 32768);
    float s1 = 0.f, s2 = 0.f;
    for (int i = threadIdx.x; i < 8192; i += 1024) {
        float4 v = xp[i];
        s1 += v.x + v.y + v.z + v.w;
        s2 += v.x*v.x + v.y*v.y + v.z*v.z + v.w*v.w;
    }
    #pragma unroll
    for (int off = 32; off; off >>= 1) {
        s1 += __shfl_down(s1, off);
        s2 += __shfl_down(s2, off);
    }
    __shared__ float r1[16], r2[16];
    int wid = threadIdx.x >> 6;
    if ((threadIdx.x & 63) == 0) { r1[wid] = s1; r2[wid] = s2; }
    __syncthreads();
    if (threadIdx.x == 0) {
        float a = 0.f, b = 0.f;
        #pragma unroll
        for (int i = 0; i < 16; ++i) { a += r1[i]; b += r2[i]; }
        float mean = a * (1.f/32768.f);
        float var  = b * (1.f/32768.f) - mean*mean;
        stats[bg*2]   = mean;
        stats[bg*2+1] = rsqrtf(var + 1e-5f);
    }
}

// ------------- convert + transpose weights to bf16 [N][K] so B-frags are contiguous -------------
__global__ void k_cvt_w(const float* __restrict__ wqkv, const float* __restrict__ wout,
                        unsigned short* __restrict__ wqkvT, unsigned short* __restrict__ woutT) {
    int i = blockIdx.x * 256 + threadIdx.x;
    if (i < 196608) {                       // w_qkv [256][768] -> [768][256]
        int k = i / 768, n = i - k * 768;
        wqkvT[n*256 + k] = f2bf(wqkv[i]);
    }
    if (i < 65536) {                        // w_out [256][256] -> [256][256]^T
        int k = i >> 8, n = i & 255;
        woutT[n*256 + k] = f2bf(wout[i]);
    }
}

// ------- normalize + transpose: x[b][c][s] fp32 -> h[b][s][c] bf16 via 64x64 LDS tile -------
__global__ __launch_bounds__(256) void k_gn_norm(
    const float* __restrict__ x, const float* __restrict__ gamma,
    const float* __restrict__ beta, const float* __restrict__ stats,
    unsigned short* __restrict__ h) {
    __shared__ unsigned short t[64][72];          // pad 8 -> decent bank spread
    int s0 = blockIdx.x * 64, c0 = blockIdx.y * 64, b = blockIdx.z;
    int tid = threadIdx.x;
    int sl = (tid & 15) * 4;                      // float4 along s
    int cr = tid >> 4;
    #pragma unroll
    for (int p = 0; p < 4; ++p) {
        int c = c0 + cr + p * 16;
        float4 v = *(const float4*)&x[(b*256 + c)*4096 + s0 + sl];
        int sg = (b*32 + (c >> 3)) * 2;
        float mean = stats[sg], rstd = stats[sg+1];
        float sa = rstd * gamma[c];
        float sb = beta[c] - mean * sa;
        ushort4 pk;
        pk.x = f2bf(v.x*sa + sb); pk.y = f2bf(v.y*sa + sb);
        pk.z = f2bf(v.z*sa + sb); pk.w = f2bf(v.w*sa + sb);
        *(ushort4*)&t[cr + p*16][sl] = pk;
    }
    __syncthreads();
    int sr = tid >> 2;                            // 0..63 (s row)
    int cc = (tid & 3) * 16;                      // 16 channels per thread
    unsigned rr[8];
    #pragma unroll
    for (int j = 0; j < 8; ++j)
        rr[j] = (unsigned)t[cc + 2*j][sr] | ((unsigned)t[cc + 2*j + 1][sr] << 16);
    unsigned short* hp = &h[(b*4096 + s0 + sr)*256 + c0];
    *(uint4*)&hp[cc]     = make_uint4(rr[0], rr[1], rr[2], rr[3]);
    *(uint4*)&hp[cc + 8] = make_uint4(rr[4], rr[5], rr[6], rr[7]);
}

// ---------------- QKV GEMM: h[16384][256] @ wqkvT -> q,k [bh][S][64], vT [bh][64][S] ----------------
// Q gets 0.125 * log2(e) folded in (attention softmax runs in exp2 domain).
__global__ __launch_bounds__(256) void k_qkv(
    const unsigned short* __restrict__ h, const unsigned short* __restrict__ wT,
    const float* __restrict__ bqkv,
    unsigned short* __restrict__ q, unsigned short* __restrict__ kk,
    unsigned short* __restrict__ vT) {
    int mt = blockIdx.x, head = blockIdx.y;
    int tid = threadIdx.x;
    int wid = tid >> 6, lane = tid & 63;
    int g = lane >> 4, li = lane & 15;
    int m0 = mt * 64 + wid * 16;
    int row = m0 + li;
    f32x4 acc[12];
    #pragma unroll
    for (int nt = 0; nt < 12; ++nt) acc[nt] = (f32x4){0.f,0.f,0.f,0.f};
    #pragma unroll
    for (int kt = 0; kt < 8; ++kt) {
        short8 a = *(const short8*)&h[row*256 + kt*32 + g*8];
        #pragma unroll
        for (int nt = 0; nt < 12; ++nt) {
            int n = head*192 + nt*16 + li;
            short8 b = *(const short8*)&wT[n*256 + kt*32 + g*8];
            acc[nt] = __builtin_amdgcn_mfma_f32_16x16x32_bf16(a, b, acc[nt], 0, 0, 0);
        }
    }
    int b = m0 >> 12;
    int s0 = m0 & 4095;
    int bh = b*4 + head;
    #pragma unroll
    for (int nt = 0; nt < 12; ++nt) {
        int ng = head*192 + nt*16 + li;
        float bias = bqkv[ng];
        int d = (nt & 3)*16 + li;
        if ((nt >> 2) == 2) {                         // V -> transposed [bh][d][s]
            ushort4 pk;
            pk.x = f2bf(acc[nt][0] + bias); pk.y = f2bf(acc[nt][1] + bias);
            pk.z = f2bf(acc[nt][2] + bias); pk.w = f2bf(acc[nt][3] + bias);
            *(ushort4*)&vT[(bh*64 + d)*4096 + s0 + g*4] = pk;
        } else if ((nt >> 2) == 0) {                  // Q (scale 0.125*log2e folded in)
            #pragma unroll
            for (int r = 0; r < 4; ++r)
                q[(bh*4096 + s0 + g*4 + r)*64 + d] = f2bf((acc[nt][r] + bias) * 0.1803368801f);
        } else {                                      // K
            #pragma unroll
            for (int r = 0; r < 4; ++r)
                kk[(bh*4096 + s0 + g*4 + r)*64 + d] = f2bf(acc[nt][r] + bias);
        }
    }
}

// ---------------- flash attention ----------------
// block = 8 waves (512 thr), Q-tile 128 (16 rows/wave), KV tiles of 64.
// K,V tiles staged in LDS (global_load_lds w16, XOR-swizzled source, double-buffered,
// counted vmcnt + raw barriers). Softmax in exp2 domain with deferred rescale.
__global__ __launch_bounds__(512) void k_attn(
    const unsigned short* __restrict__ q, const unsigned short* __restrict__ kk,
    const unsigned short* __restrict__ vT, unsigned short* __restrict__ ao) {
    __shared__ unsigned short kbuf[2][4096];      // 2 x 8KB  [64 j][64 d] swizzled
    __shared__ unsigned short vbuf[2][4096];      // 2 x 8KB  [64 d][64 s] swizzled
    __shared__ unsigned short pT[8][16][72];      // per-wave P^T staging

    int qt = blockIdx.x, bh = blockIdx.y;
    int tid = threadIdx.x;
    int wid = tid >> 6, lane = tid & 63;
    int g = lane >> 4, li = lane & 15;
    int sw_li = (li & 7) << 4;

    int qbase = qt * 128 + wid * 16;
    int qrow = bh * 4096 + qbase + li;
    short8 bq0 = *(const short8*)&q[qrow*64 + g*8];
    short8 bq1 = *(const short8*)&q[qrow*64 + 32 + g*8];

    // staging geometry: thread t covers LDS bytes [t*16, t*16+16) of the 8KB tile
    unsigned p16  = tid * 16;
    unsigned srow = p16 >> 7;                         // tile row 0..63
    unsigned ksw  = p16 ^ ((srow & 7) << 4);          // K: tile is 8KB contiguous in global
    unsigned vcol = (p16 & 127u) ^ ((srow & 7) << 4); // V: rows stride 8192B in global
    const char* kbase = (const char*)kk + ((size_t)(bh*4096) * 64) * 2;
    const char* vbase = (const char*)vT + ((size_t)(bh*64 + srow)) * 8192;
    char* kdst0 = (char*)&kbuf[0][0] + (wid << 10);
    char* kdst1 = (char*)&kbuf[1][0] + (wid << 10);
    char* vdst0 = (char*)&vbuf[0][0] + (wid << 10);
    char* vdst1 = (char*)&vbuf[1][0] + (wid << 10);

    f32x4 o[4];
    #pragma unroll
    for (int dt = 0; dt < 4; ++dt) o[dt] = (f32x4){0.f,0.f,0.f,0.f};
    float m_run = -1e30f, l_run = 0.f;
    char* pTw = (char*)&pT[wid][0][0];

    // prologue stage kt=0 into buf0
    gl_lds16(kbase + ksw, kdst0);
    gl_lds16(vbase + vcol, vdst0);

    int cur = 0;
    for (int kt = 0; kt < 64; ++kt) {
        if (kt < 63) {                                // stage kt+1 into buf[cur^1]
            size_t nb = (size_t)(kt + 1) * 8192;      // byte advance of K tile / V col
            gl_lds16(kbase + nb + ksw, cur ? kdst0 : kdst1);
            gl_lds16(vbase + (size_t)(kt + 1) * 128 + vcol, cur ? vdst0 : vdst1);
            asm volatile("s_waitcnt vmcnt(2)" ::: "memory");
        } else {
            asm volatile("s_waitcnt vmcnt(0)" ::: "memory");
        }
        __builtin_amdgcn_s_barrier();
        asm volatile("" ::: "memory");

        const char* kb = (const char*)&kbuf[cur][0];
        const char* vb = (const char*)&vbuf[cur][0];

        // S^T = K-tile x Q
        f32x4 sT[4];
        #pragma unroll
        for (int f = 0; f < 4; ++f) sT[f] = (f32x4){0.f,0.f,0.f,0.f};
        #pragma unroll
        for (int f = 0; f < 4; ++f) {
            const char* rowp = kb + (f*16 + li) * 128;
            short8 ka0 = *(const short8*)(rowp + ((g*16) ^ sw_li));
            short8 ka1 = *(const short8*)(rowp + ((64 + g*16) ^ sw_li));
            sT[f] = __builtin_amdgcn_mfma_f32_16x16x32_bf16(ka0, bq0, sT[f], 0, 0, 0);
            sT[f] = __builtin_amdgcn_mfma_f32_16x16x32_bf16(ka1, bq1, sT[f], 0, 0, 0);
        }

        // online softmax (exp2 domain), row i = li lane-local, partials across g
        float mx = -1e30f;
        #pragma unroll
        for (int f = 0; f < 4; ++f)
            #pragma unroll
            for (int r = 0; r < 4; ++r) mx = fmaxf(mx, sT[f][r]);
        mx = fmaxf(mx, __shfl_xor(mx, 16));
        mx = fmaxf(mx, __shfl_xor(mx, 32));
        if (__any(mx > m_run)) {                      // deferred rescale
            float m_new = fmaxf(m_run, mx);
            float fac = fexp2(m_run - m_new);
            l_run *= fac;
            #pragma unroll
            for (int dt = 0; dt < 4; ++dt) {
                o[dt][0] *= fac; o[dt][1] *= fac; o[dt][2] *= fac; o[dt][3] *= fac;
            }
            m_run = m_new;
        }
        float psum = 0.f;
        float pv[4][4];
        #pragma unroll
        for (int f = 0; f < 4; ++f)
            #pragma unroll
            for (int r = 0; r < 4; ++r) {
                float pe = fexp2(sT[f][r] - m_run);
                pv[f][r] = pe; psum += pe;
            }
        psum += __shfl_xor(psum, 16);
        psum += __shfl_xor(psum, 32);
        l_run += psum;

        // pack P^T -> per-wave LDS (wave-private, no barrier)
        #pragma unroll
        for (int f = 0; f < 4; ++f) {
            unsigned lo = cvt_pk_bf16(pv[f][0], pv[f][1]);
            unsigned hi = cvt_pk_bf16(pv[f][2], pv[f][3]);
            *(uint2*)(pTw + li*144 + f*32 + g*8) = make_uint2(lo, hi);
        }

        // O^T += V^T x P^T
        #pragma unroll
        for (int ks = 0; ks < 2; ++ks) {
            short8 pb = *(const short8*)(pTw + li*144 + ks*64 + g*16);
            #pragma unroll
            for (int dt = 0; dt < 4; ++dt) {
                const char* vrow = vb + (dt*16 + li) * 128;
                short8 va = *(const short8*)(vrow + ((ks*64 + g*16) ^ sw_li));
                o[dt] = __builtin_amdgcn_mfma_f32_16x16x32_bf16(va, pb, o[dt], 0, 0, 0);
            }
        }

        asm volatile("" ::: "memory");
        __builtin_amdgcn_s_barrier();
        cur ^= 1;
    }

    float inv = 1.f / l_run;
    int b = bh >> 2, hh = bh & 3;
    int s = qbase + li;
    #pragma unroll
    for (int dt = 0; dt < 4; ++dt) {
        ushort4 pk;
        pk.x = f2bf(o[dt][0]*inv); pk.y = f2bf(o[dt][1]*inv);
        pk.z = f2bf(o[dt][2]*inv); pk.w = f2bf(o[dt][3]*inv);
        *(ushort4*)&ao[(b*4096 + s)*256 + hh*64 + dt*16 + g*4] = pk;
    }
}

// ---------------- out GEMM + bias + residual, transposed float4 store ----------------
__global__ __launch_bounds__(256) void k_out(
    const unsigned short* __restrict__ ao, const unsigned short* __restrict__ wT,
    const float* __restrict__ bout, const float* __restrict__ x,
    float* __restrict__ out) {
    int mt = blockIdx.x, ntb = blockIdx.y;
    int tid = threadIdx.x;
    int wid = tid >> 6, lane = tid & 63;
    int g = lane >> 4, li = lane & 15;
    int m0 = mt * 64 + wid * 16;
    int row = m0 + li;
    f32x4 acc[4];
    #pragma unroll
    for (int nt = 0; nt < 4; ++nt) acc[nt] = (f32x4){0.f,0.f,0.f,0.f};
    #pragma unroll
    for (int kt = 0; kt < 8; ++kt) {
        short8 a = *(const short8*)&ao[row*256 + kt*32 + g*8];
        #pragma unroll
        for (int nt = 0; nt < 4; ++nt) {
            int n = ntb*64 + nt*16 + li;
            short8 b = *(const short8*)&wT[n*256 + kt*32 + g*8];
            acc[nt] = __builtin_amdgcn_mfma_f32_16x16x32_bf16(a, b, acc[nt], 0, 0, 0);
        }
    }
    int b = m0 >> 12;
    int s0 = (m0 & 4095) + g*4;
    #pragma unroll
    for (int nt = 0; nt < 4; ++nt) {
        int c = ntb*64 + nt*16 + li;
        float bias = bout[c];
        int base = (b*256 + c)*4096 + s0;
        float4 xr = *(const float4*)&x[base];
        float4 ov;
        ov.x = acc[nt][0] + bias + xr.x;
        ov.y = acc[nt][1] + bias + xr.y;
        ov.z = acc[nt][2] + bias + xr.z;
        ov.w = acc[nt][3] + bias + xr.w;
        *(float4*)&out[base] = ov;
    }
}

extern "C" void kernel_launch(void* const* d_in, const int* in_sizes, int n_in,
                              void* d_out, int out_size, void* d_ws, size_t ws_size,
                              hipStream_t stream) {
    (void)in_sizes; (void)n_in; (void)out_size; (void)ws_size;
    const float* x     = (const float*)d_in[0];
    const float* gamma = (const float*)d_in[1];
    const float* beta  = (const float*)d_in[2];
    const float* wqkv  = (const float*)d_in[3];
    const float* bqkv  = (const float*)d_in[4];
    const float* wout  = (const float*)d_in[5];
    const float* bout  = (const float*)d_in[6];
    float* out = (float*)d_out;

    char* ws = (char*)d_ws;
    unsigned short* h     = (unsigned short*)(ws);                    // 8 MB  [B*S][256] bf16
    unsigned short* q     = (unsigned short*)(ws + (8u<<20));         // 8 MB  [bh][S][64]
    unsigned short* kk    = (unsigned short*)(ws + (16u<<20));        // 8 MB  [bh][S][64]
    unsigned short* vT    = (unsigned short*)(ws + (24u<<20));        // 8 MB  [bh][64][S]
    unsigned short* ao    = (unsigned short*)(ws + (32u<<20));        // 8 MB  [B*S][256]
    unsigned short* wqkvT = (unsigned short*)(ws + (40u<<20));        // 384 KB [768][256]
    unsigned short* woutT = (unsigned short*)(ws + (40u<<20) + 393216);// 128 KB [256][256]
    float*          stats = (float*)(ws + (40u<<20) + 524288);        // 1 KB

    k_gn_stats<<<128, 1024, 0, stream>>>(x, stats);
    k_cvt_w<<<768, 256, 0, stream>>>(wqkv, wout, wqkvT, woutT);
    k_gn_norm<<<dim3(64, 4, 4), 256, 0, stream>>>(x, gamma, beta, stats, h);
    k_qkv<<<dim3(256, 4), 256, 0, stream>>>(h, wqkvT, bqkv, q, kk, vT);
    k_attn<<<dim3(32, 16), 512, 0, stream>>>(q, kk, vT, ao);
    k_out<<<dim3(256, 4), 256, 0, stream>>>(ao, woutT, bout, x, out);
}